// Round 10
// baseline (247.284 us; speedup 1.0000x reference)
//
#include <hip/hip_runtime.h>
#include <hip/hip_bf16.h>
#include <stdint.h>

// RecurrentReadout: x[16,256,1024,8,8] -> spatial mean -> linear (W[1024,1024],b) -> diag recurrence over T.
// R10: gemmscan WITHOUT LDS staging. Operands are L2-resident (per-XCD slice: 1MB A + 2MB W < 4MiB L2);
// MFMA frags read directly from global (row-major; one frag instr = 16 rows x 64B lines, fully utilized
// across the 4 kb-slots). Zero barriers in the K-loop -> no vmcnt(0) drain at 1 wave/SIMD; waves
// pipeline loads/MFMA freely. LDS reduced to the 1KB scan-combine buffer. Scan epilogue = R9 verbatim.
// k_mean unchanged (R5 lesson: barrier-free streaming).

typedef __attribute__((ext_vector_type(8))) short bf16x8;   // 8 bf16 = 4 VGPRs (MFMA A/B frag)
typedef __attribute__((ext_vector_type(4))) float f32x4;    // MFMA C/D frag

__device__ __forceinline__ unsigned short f2bf(float f) {
  union { float f; unsigned int u; } c; c.f = f;
  unsigned int u = c.u;
  return (unsigned short)((u + 0x7FFFu + ((u >> 16) & 1u)) >> 16);  // RNE
}

// ---------------- spatial mean (+ W fp32->bf16 piggybacked) ----------------
__global__ __launch_bounds__(256) void k_mean(const float* __restrict__ x,
                                              unsigned short* __restrict__ xm,
                                              const float* __restrict__ W,
                                              unsigned short* __restrict__ Wb) {
  const int tid = threadIdx.x;
  const int wi = blockIdx.x * 256 + tid;
  if (wi < 262144) {
    float4 v = *(const float4*)(W + wi * 4);
    ushort4 o;
    o.x = f2bf(v.x); o.y = f2bf(v.y); o.z = f2bf(v.z); o.w = f2bf(v.w);
    *(ushort4*)(Wb + wi * 4) = o;
  }
  const int sub = tid & 15;
  const int grp = tid >> 4;
  for (int base = blockIdx.x * 16; base < (1 << 22); base += gridDim.x * 16) {
    int seg = base + grp;
    const float4 v = *(const float4*)(x + (long)seg * 64 + sub * 4);
    float s = v.x + v.y + v.z + v.w;
    s += __shfl_xor(s, 1);
    s += __shfl_xor(s, 2);
    s += __shfl_xor(s, 4);
    s += __shfl_xor(s, 8);
    if (sub == 0) xm[seg] = f2bf(s * 0.015625f);
  }
}

// ---------------- fused GEMM + scan (no LDS staging) ----------------
__global__ __launch_bounds__(256) void k_gemmscan(const unsigned short* __restrict__ A,
                                                  const unsigned short* __restrict__ Bm,
                                                  const float* __restrict__ bias,
                                                  const float* __restrict__ r0,
                                                  const float* __restrict__ alpha,
                                                  float* __restrict__ out) {
  __shared__ float F[256];  // [wave][64] cross-wave scan carries
  const int bid = blockIdx.x;
  const int nb  = (bid & 7) * 32 + (bid >> 3);  // XCD-chunked bijective (256 = 8*32): XCD owns 2 b x 16 nt
  const int b   = nb >> 4;
  const int n0  = (nb & 15) * 64;
  const int m0  = b * 256;

  const int lane = threadIdx.x & 63;
  const int w    = threadIdx.x >> 6;   // wave id: t-range [64w, 64w+64)
  const int r16  = lane & 15;
  const int kb   = lane >> 4;          // k-block within MFMA frag
  const int h    = kb;                 // scan h-group (t = 64w + 16i + 4h + q)

  f32x4 acc[4][4] = {};                // [i: m-frag][j: n-frag]

  // Direct-from-L2 fragment pointers. Frag instr: lanes cover 16 rows (2KB stride) x 64B lines,
  // each line fully consumed by the 4 kb-slots of the same instruction.
  const unsigned short* ap[4];
  const unsigned short* bp[4];
#pragma unroll
  for (int i = 0; i < 4; i++) ap[i] = A  + (long)(m0 + w * 64 + i * 16 + r16) * 1024 + kb * 8;
#pragma unroll
  for (int j = 0; j < 4; j++) bp[j] = Bm + (long)(n0 + j * 16 + r16) * 1024 + kb * 8;

#pragma unroll 2
  for (int t = 0; t < 16; t++) {
    bf16x8 af[2][4], bf_[2][4];
#pragma unroll
    for (int ks = 0; ks < 2; ks++) {
#pragma unroll
      for (int i = 0; i < 4; i++) af[ks][i] = *(const bf16x8*)(ap[i] + t * 64 + ks * 32);
#pragma unroll
      for (int j = 0; j < 4; j++) bf_[ks][j] = *(const bf16x8*)(bp[j] + t * 64 + ks * 32);
    }
#pragma unroll
    for (int ks = 0; ks < 2; ks++)
#pragma unroll
      for (int i = 0; i < 4; i++)
#pragma unroll
        for (int j = 0; j < 4; j++)
          acc[i][j] = __builtin_amdgcn_mfma_f32_16x16x32_bf16(af[ks][i], bf_[ks][j], acc[i][j], 0, 0, 0);
  }

  // ---- in-register scan over t = 64w + 16i + 4h + q (C/D: col=lane&15, row=(lane>>4)*4+q) ----
  float a1[4], a2[4], a3[4], a4[4], a8[4], a12[4], a16[4], a64[4], p4h[4], r0v[4], Cw[4];
#pragma unroll
  for (int j = 0; j < 4; j++) {
    const int col = n0 + j * 16 + r16;
    const float a = alpha[col];
    a1[j] = a; a2[j] = a * a; a3[j] = a2[j] * a; a4[j] = a2[j] * a2[j];
    a8[j] = a4[j] * a4[j]; a12[j] = a8[j] * a4[j]; a16[j] = a8[j] * a8[j];
    const float a32 = a16[j] * a16[j]; a64[j] = a32 * a32;
    p4h[j] = (h == 0) ? 1.f : (h == 1) ? a4[j] : (h == 2) ? a8[j] : a12[j];
    r0v[j] = r0[b * 1024 + col];
    const float bb = bias[col];
    Cw[j] = 0.f;
#pragma unroll
    for (int i = 0; i < 4; i++) {
      const float u0 = acc[i][j][0] + bb, u1 = acc[i][j][1] + bb;
      const float u2 = acc[i][j][2] + bb, u3 = acc[i][j][3] + bb;
      const float l0 = u0;
      const float l1 = fmaf(a1[j], l0, u1);
      const float l2 = fmaf(a1[j], l1, u2);
      const float l3 = fmaf(a1[j], l2, u3);
      // weighted Hillis-Steele over h: x_h = sum_{g<=h} a^{4(h-g)} S_g, S = l3
      float xv = l3;
      float t1 = __shfl_up(xv, 16); if (h >= 1) xv = fmaf(a4[j], t1, xv);
      float t2 = __shfl_up(xv, 32); if (h >= 2) xv = fmaf(a8[j], t2, xv);
      float P  = __shfl_up(xv, 16); if (h == 0) P = 0.f;     // exclusive over h
      const float G = fmaf(p4h[j], Cw[j], P);                 // carry into (i,h)
      acc[i][j][0] = fmaf(a1[j], G, l0);
      acc[i][j][1] = fmaf(a2[j], G, l1);
      acc[i][j][2] = fmaf(a3[j], G, l2);
      acc[i][j][3] = fmaf(a4[j], G, l3);
      const float xe = __shfl(xv, r16 + 48);                  // inclusive at h=3 (broadcast)
      Cw[j] = fmaf(a16[j], Cw[j], xe);                        // carry into frag i+1
    }
  }

  // ---- cross-wave combine: R = a^{64} ... via F[4][64] ----
  if (h == 0) {
#pragma unroll
    for (int j = 0; j < 4; j++) F[w * 64 + j * 16 + r16] = Cw[j];
  }
  __syncthreads();
  float R[4];
#pragma unroll
  for (int j = 0; j < 4; j++) {
    R[j] = r0v[j];
    for (int v = 0; v < w; v++) R[j] = fmaf(a64[j], R[j], F[v * 64 + j * 16 + r16]);
    float gi = p4h[j] * R[j];
#pragma unroll
    for (int i = 0; i < 4; i++) {
      acc[i][j][0] = fmaf(a1[j], gi, acc[i][j][0]);
      acc[i][j][1] = fmaf(a2[j], gi, acc[i][j][1]);
      acc[i][j][2] = fmaf(a3[j], gi, acc[i][j][2]);
      acc[i][j][3] = fmaf(a4[j], gi, acc[i][j][3]);
      gi *= a16[j];
    }
  }

  // ---- stores: r_seq ----
#pragma unroll
  for (int i = 0; i < 4; i++)
#pragma unroll
    for (int j = 0; j < 4; j++) {
      const long mrow = m0 + w * 64 + i * 16 + h * 4;
      const int  n    = n0 + j * 16 + r16;
#pragma unroll
      for (int q = 0; q < 4; q++)
        out[(mrow + q) * 1024 + n] = acc[i][j][q];
    }
  // r_final = a^64 R_2 + C_3 (wave 3 holds R_2 in R[j], C_3 in F[192+..])
  if (w == 3 && h == 0) {
#pragma unroll
    for (int j = 0; j < 4; j++)
      out[(1 << 22) + b * 1024 + n0 + j * 16 + r16] = fmaf(a64[j], R[j], F[192 + j * 16 + r16]);
  }
}

extern "C" void kernel_launch(void* const* d_in, const int* in_sizes, int n_in,
                              void* d_out, int out_size, void* d_ws, size_t ws_size,
                              hipStream_t stream) {
  const float* x     = (const float*)d_in[0];
  const float* r0    = (const float*)d_in[1];
  const float* W     = (const float*)d_in[2];
  const float* b     = (const float*)d_in[3];
  const float* alpha = (const float*)d_in[4];
  float* out = (float*)d_out;

  unsigned short* xm = (unsigned short*)d_ws;                        // 8 MiB: [4096][1024] bf16
  unsigned short* Wb = (unsigned short*)((char*)d_ws + (8u << 20));  // 2 MiB: [1024][1024] bf16

  k_mean<<<2048, 256, 0, stream>>>(x, xm, W, Wb);
  k_gemmscan<<<256, 256, 0, stream>>>(xm, Wb, b, r0, alpha, out);
}

// Round 11
// 226.791 us; speedup vs baseline: 1.0904x; 1.0904x over previous
//
#include <hip/hip_runtime.h>
#include <hip/hip_bf16.h>
#include <stdint.h>

// RecurrentReadout: x[16,256,1024,8,8] -> spatial mean -> linear (W[1024,1024],b) -> diag recurrence over T.
// R11 = R9's gemmscan (best, LDS-staged; R10's no-LDS frag reads were non-coalesced, -19us) +
// rebuilt k_mean: contiguous per-block segment ranges, unroll x4 batched loads (4 outstanding
// 1KB reqs/wave), xm results staged in LDS and flushed once with coalesced 16B stores
// (eliminates per-iter 8B partial-line writes).

typedef __attribute__((ext_vector_type(8))) short bf16x8;   // 8 bf16 = 4 VGPRs (MFMA A/B frag)
typedef __attribute__((ext_vector_type(4))) float f32x4;    // MFMA C/D frag
typedef __attribute__((ext_vector_type(8))) unsigned short u16x8;

__device__ __forceinline__ unsigned short f2bf(float f) {
  union { float f; unsigned int u; } c; c.f = f;
  unsigned int u = c.u;
  return (unsigned short)((u + 0x7FFFu + ((u >> 16) & 1u)) >> 16);  // RNE
}

// ---------------- spatial mean (+ W fp32->bf16 piggybacked) ----------------
// Block bid owns segments [bid*2048, +2048): 128 iters x 16 segs, 4KB contiguous read per iter.
// Unroll x4: batch 4 independent float4 loads before the shuffle chains. Results -> LDS sxm[2048],
// one coalesced 4KB flush at the end (ushort8 per thread).
__global__ __launch_bounds__(256) void k_mean(const float* __restrict__ x,
                                              unsigned short* __restrict__ xm,
                                              const float* __restrict__ W,
                                              unsigned short* __restrict__ Wb) {
  __shared__ unsigned short sxm[2048];
  const int tid = threadIdx.x;
  const int bid = blockIdx.x;
  // piggyback: first 262144 threads convert one float4 of W (1M elems total)
  const int wi = bid * 256 + tid;
  if (wi < 262144) {
    float4 v = *(const float4*)(W + wi * 4);
    ushort4 o;
    o.x = f2bf(v.x); o.y = f2bf(v.y); o.z = f2bf(v.z); o.w = f2bf(v.w);
    *(ushort4*)(Wb + wi * 4) = o;
  }
  const int sub = tid & 15;
  const int grp = tid >> 4;
  const float* xb = x + (long)bid * 131072 + grp * 64 + sub * 4;  // block's 8MB x panel
#pragma unroll 1
  for (int it = 0; it < 128; it += 4) {
    float4 v[4];
#pragma unroll
    for (int u = 0; u < 4; u++) v[u] = *(const float4*)(xb + (it + u) * 1024);
#pragma unroll
    for (int u = 0; u < 4; u++) {
      float s = v[u].x + v[u].y + v[u].z + v[u].w;
      s += __shfl_xor(s, 1);
      s += __shfl_xor(s, 2);
      s += __shfl_xor(s, 4);
      s += __shfl_xor(s, 8);
      if (sub == 0) sxm[(it + u) * 16 + grp] = f2bf(s * 0.015625f);
    }
  }
  __syncthreads();
  *(u16x8*)(xm + (long)bid * 2048 + tid * 8) = *(const u16x8*)(sxm + tid * 8);
}

// ---------------- fused GEMM + scan (R9, LDS-staged 2-phase dbuf) ----------------
#define GLDS16(g, l) \
  __builtin_amdgcn_global_load_lds((const __attribute__((address_space(1))) void*)(g), \
                                   (__attribute__((address_space(3))) void*)(l), 16, 0, 0)

__global__ __launch_bounds__(256, 1) void k_gemmscan(const unsigned short* __restrict__ A,
                                                     const unsigned short* __restrict__ Bm,
                                                     const float* __restrict__ bias,
                                                     const float* __restrict__ r0,
                                                     const float* __restrict__ alpha,
                                                     float* __restrict__ out) {
  __shared__ unsigned short lds[2][20480];  // per buf: A[256][64] (32KB) + B[64][64] (8KB)
  const int bid = blockIdx.x;
  const int nb  = (bid & 7) * 32 + (bid >> 3);  // XCD-chunked bijective (256 = 8*32)
  const int b   = nb >> 4;
  const int n0  = (nb & 15) * 64;
  const int m0  = b * 256;

  const int tid  = threadIdx.x;
  const int lane = tid & 63;
  const int w    = tid >> 6;       // wave id: t-range [64w, 64w+64)
  const int r16  = lane & 15;
  const int kb   = lane >> 4;
  const int h    = lane >> 4;      // scan h-group (t = 16i + 4h + q)

  f32x4 acc[4][4] = {};            // [i: m-frag][j: n-frag]

  const int srow8  = tid >> 3;     // 0..31
  const int sslot8 = tid & 7;
  const int gkoff  = (sslot8 ^ (srow8 & 7)) << 3;  // pre-swizzled k-offset

  const unsigned short* ag[8];
  const unsigned short* bg[2];
#pragma unroll
  for (int ra = 0; ra < 8; ra++) ag[ra] = A  + (long)(m0 + ra * 32 + srow8) * 1024 + gkoff;
#pragma unroll
  for (int rb = 0; rb < 2; rb++) bg[rb] = Bm + (long)(n0 + rb * 32 + srow8) * 1024 + gkoff;

  auto stage = [&](int t) {
    const int k0 = t * 64;
    char* Ab = (char*)&lds[t & 1][0];
    char* Bb = (char*)&lds[t & 1][16384];
#pragma unroll
    for (int ra = 0; ra < 8; ra++) GLDS16(ag[ra] + k0, Ab + tid * 16 + ra * 4096);
#pragma unroll
    for (int rb = 0; rb < 2; rb++) GLDS16(bg[rb] + k0, Bb + tid * 16 + rb * 4096);
  };

  auto compute = [&](int t) {
    const unsigned short* Ab = &lds[t & 1][0];
    const unsigned short* Bb = &lds[t & 1][16384];
    bf16x8 af[2][4], bf_[2][4];
#pragma unroll
    for (int ks = 0; ks < 2; ks++) {
#pragma unroll
      for (int i = 0; i < 4; i++) {
        const int rr = w * 64 + i * 16 + r16;
        af[ks][i] = *(const bf16x8*)(Ab + rr * 64 + (((ks * 4 + kb) ^ (rr & 7)) << 3));
      }
#pragma unroll
      for (int j = 0; j < 4; j++) {
        const int cc = j * 16 + r16;
        bf_[ks][j] = *(const bf16x8*)(Bb + cc * 64 + (((ks * 4 + kb) ^ (cc & 7)) << 3));
      }
    }
#pragma unroll
    for (int ks = 0; ks < 2; ks++)
#pragma unroll
      for (int i = 0; i < 4; i++)
#pragma unroll
        for (int j = 0; j < 4; j++)
          acc[i][j] = __builtin_amdgcn_mfma_f32_16x16x32_bf16(af[ks][i], bf_[ks][j], acc[i][j], 0, 0, 0);
  };

  stage(0);
  __syncthreads();
#pragma unroll 1
  for (int t = 0; t < 16; t++) {
    if (t < 15) stage(t + 1);
    compute(t);
    __syncthreads();
  }

  // ---- in-register scan over t = 64w + 16i + 4h + q (C/D: col=lane&15, row=(lane>>4)*4+q) ----
  float a1[4], a2[4], a3[4], a4[4], a8[4], a12[4], a16[4], a64[4], p4h[4], r0v[4], Cw[4];
#pragma unroll
  for (int j = 0; j < 4; j++) {
    const int col = n0 + j * 16 + r16;
    const float a = alpha[col];
    a1[j] = a; a2[j] = a * a; a3[j] = a2[j] * a; a4[j] = a2[j] * a2[j];
    a8[j] = a4[j] * a4[j]; a12[j] = a8[j] * a4[j]; a16[j] = a8[j] * a8[j];
    const float a32 = a16[j] * a16[j]; a64[j] = a32 * a32;
    p4h[j] = (h == 0) ? 1.f : (h == 1) ? a4[j] : (h == 2) ? a8[j] : a12[j];
    r0v[j] = r0[b * 1024 + col];
    const float bb = bias[col];
    Cw[j] = 0.f;
#pragma unroll
    for (int i = 0; i < 4; i++) {
      const float u0 = acc[i][j][0] + bb, u1 = acc[i][j][1] + bb;
      const float u2 = acc[i][j][2] + bb, u3 = acc[i][j][3] + bb;
      const float l0 = u0;
      const float l1 = fmaf(a1[j], l0, u1);
      const float l2 = fmaf(a1[j], l1, u2);
      const float l3 = fmaf(a1[j], l2, u3);
      float xv = l3;
      float t1 = __shfl_up(xv, 16); if (h >= 1) xv = fmaf(a4[j], t1, xv);
      float t2 = __shfl_up(xv, 32); if (h >= 2) xv = fmaf(a8[j], t2, xv);
      float P  = __shfl_up(xv, 16); if (h == 0) P = 0.f;     // exclusive over h
      const float G = fmaf(p4h[j], Cw[j], P);                 // carry into (i,h)
      acc[i][j][0] = fmaf(a1[j], G, l0);
      acc[i][j][1] = fmaf(a2[j], G, l1);
      acc[i][j][2] = fmaf(a3[j], G, l2);
      acc[i][j][3] = fmaf(a4[j], G, l3);
      const float xe = __shfl(xv, r16 + 48);                  // inclusive at h=3
      Cw[j] = fmaf(a16[j], Cw[j], xe);                        // carry into frag i+1
    }
  }

  // ---- cross-wave combine via F[4][64] ----
  float* F = (float*)&lds[0][0];  // safe: past last k-loop barrier; scan was reg-only
  if (h == 0) {
#pragma unroll
    for (int j = 0; j < 4; j++) F[w * 64 + j * 16 + r16] = Cw[j];
  }
  __syncthreads();
  float R[4];
#pragma unroll
  for (int j = 0; j < 4; j++) {
    R[j] = r0v[j];
    for (int v = 0; v < w; v++) R[j] = fmaf(a64[j], R[j], F[v * 64 + j * 16 + r16]);
    float gi = p4h[j] * R[j];
#pragma unroll
    for (int i = 0; i < 4; i++) {
      acc[i][j][0] = fmaf(a1[j], gi, acc[i][j][0]);
      acc[i][j][1] = fmaf(a2[j], gi, acc[i][j][1]);
      acc[i][j][2] = fmaf(a3[j], gi, acc[i][j][2]);
      acc[i][j][3] = fmaf(a4[j], gi, acc[i][j][3]);
      gi *= a16[j];
    }
  }

  // ---- stores: r_seq ----
#pragma unroll
  for (int i = 0; i < 4; i++)
#pragma unroll
    for (int j = 0; j < 4; j++) {
      const long mrow = m0 + w * 64 + i * 16 + h * 4;
      const int  n    = n0 + j * 16 + r16;
#pragma unroll
      for (int q = 0; q < 4; q++)
        out[(mrow + q) * 1024 + n] = acc[i][j][q];
    }
  // r_final = a^64 R_2 + C_3 (wave 3 holds R_2 in R[j], C_3 in F[192+..])
  if (w == 3 && h == 0) {
#pragma unroll
    for (int j = 0; j < 4; j++)
      out[(1 << 22) + b * 1024 + n0 + j * 16 + r16] = fmaf(a64[j], R[j], F[192 + j * 16 + r16]);
  }
}

extern "C" void kernel_launch(void* const* d_in, const int* in_sizes, int n_in,
                              void* d_out, int out_size, void* d_ws, size_t ws_size,
                              hipStream_t stream) {
  const float* x     = (const float*)d_in[0];
  const float* r0    = (const float*)d_in[1];
  const float* W     = (const float*)d_in[2];
  const float* b     = (const float*)d_in[3];
  const float* alpha = (const float*)d_in[4];
  float* out = (float*)d_out;

  unsigned short* xm = (unsigned short*)d_ws;                        // 8 MiB: [4096][1024] bf16
  unsigned short* Wb = (unsigned short*)((char*)d_ws + (8u << 20));  // 2 MiB: [1024][1024] bf16

  k_mean<<<2048, 256, 0, stream>>>(x, xm, W, Wb);
  k_gemmscan<<<256, 256, 0, stream>>>(xm, Wb, b, r0, alpha, out);
}

// Round 12
// 198.762 us; speedup vs baseline: 1.2441x; 1.1410x over previous
//
#include <hip/hip_runtime.h>
#include <hip/hip_bf16.h>
#include <stdint.h>

// RecurrentReadout: x[16,256,1024,8,8] -> spatial mean -> linear (W[1024,1024],b) -> diag recurrence over T.
// R12 = R11 + (a) gemmscan k-loop: counted vmcnt(10) + raw s_barrier pair instead of __syncthreads
// (removes the per-step vmcnt(0) drain; stage(t+1) loads stay in flight across the barrier, T4) ;
// (b) k_mean: nontemporal x loads (stream is never reused; keeps L2 clean).

typedef __attribute__((ext_vector_type(8))) short bf16x8;   // 8 bf16 = 4 VGPRs (MFMA A/B frag)
typedef __attribute__((ext_vector_type(4))) float f32x4;    // MFMA C/D frag
typedef __attribute__((ext_vector_type(8))) unsigned short u16x8;

__device__ __forceinline__ unsigned short f2bf(float f) {
  union { float f; unsigned int u; } c; c.f = f;
  unsigned int u = c.u;
  return (unsigned short)((u + 0x7FFFu + ((u >> 16) & 1u)) >> 16);  // RNE
}

// ---------------- spatial mean (+ W fp32->bf16 piggybacked) ----------------
// Block bid owns segments [bid*2048, +2048): 128 iters x 16 segs, 4KB contiguous NT read per iter.
// Results staged in LDS, one coalesced 4KB flush (ushort8/thread) at the end.
__global__ __launch_bounds__(256) void k_mean(const float* __restrict__ x,
                                              unsigned short* __restrict__ xm,
                                              const float* __restrict__ W,
                                              unsigned short* __restrict__ Wb) {
  __shared__ unsigned short sxm[2048];
  const int tid = threadIdx.x;
  const int bid = blockIdx.x;
  // piggyback: first 262144 threads convert one float4 of W (1M elems total)
  const int wi = bid * 256 + tid;
  if (wi < 262144) {
    float4 v = *(const float4*)(W + wi * 4);
    ushort4 o;
    o.x = f2bf(v.x); o.y = f2bf(v.y); o.z = f2bf(v.z); o.w = f2bf(v.w);
    *(ushort4*)(Wb + wi * 4) = o;
  }
  const int sub = tid & 15;
  const int grp = tid >> 4;
  const float* xb = x + (long)bid * 131072 + grp * 64 + sub * 4;  // block's 512KB x panel
#pragma unroll 1
  for (int it = 0; it < 128; it += 4) {
    f32x4 v[4];
#pragma unroll
    for (int u = 0; u < 4; u++)
      v[u] = __builtin_nontemporal_load((const f32x4*)(xb + (it + u) * 1024));
#pragma unroll
    for (int u = 0; u < 4; u++) {
      float s = v[u][0] + v[u][1] + v[u][2] + v[u][3];
      s += __shfl_xor(s, 1);
      s += __shfl_xor(s, 2);
      s += __shfl_xor(s, 4);
      s += __shfl_xor(s, 8);
      if (sub == 0) sxm[(it + u) * 16 + grp] = f2bf(s * 0.015625f);
    }
  }
  __syncthreads();
  *(u16x8*)(xm + (long)bid * 2048 + tid * 8) = *(const u16x8*)(sxm + tid * 8);
}

// ---------------- fused GEMM + scan (LDS-staged, counted-vmcnt 2-barrier pipeline) ----------------
#define GLDS16(g, l) \
  __builtin_amdgcn_global_load_lds((const __attribute__((address_space(1))) void*)(g), \
                                   (__attribute__((address_space(3))) void*)(l), 16, 0, 0)

__global__ __launch_bounds__(256, 1) void k_gemmscan(const unsigned short* __restrict__ A,
                                                     const unsigned short* __restrict__ Bm,
                                                     const float* __restrict__ bias,
                                                     const float* __restrict__ r0,
                                                     const float* __restrict__ alpha,
                                                     float* __restrict__ out) {
  __shared__ unsigned short lds[2][20480];  // per buf: A[256][64] (32KB) + B[64][64] (8KB)
  const int bid = blockIdx.x;
  const int nb  = (bid & 7) * 32 + (bid >> 3);  // XCD-chunked bijective (256 = 8*32)
  const int b   = nb >> 4;
  const int n0  = (nb & 15) * 64;
  const int m0  = b * 256;

  const int tid  = threadIdx.x;
  const int lane = tid & 63;
  const int w    = tid >> 6;       // wave id: t-range [64w, 64w+64)
  const int r16  = lane & 15;
  const int kb   = lane >> 4;
  const int h    = lane >> 4;      // scan h-group (t = 16i + 4h + q)

  f32x4 acc[4][4] = {};            // [i: m-frag][j: n-frag]

  const int srow8  = tid >> 3;     // 0..31
  const int sslot8 = tid & 7;
  const int gkoff  = (sslot8 ^ (srow8 & 7)) << 3;  // pre-swizzled k-offset

  const unsigned short* ag[8];
  const unsigned short* bg[2];
#pragma unroll
  for (int ra = 0; ra < 8; ra++) ag[ra] = A  + (long)(m0 + ra * 32 + srow8) * 1024 + gkoff;
#pragma unroll
  for (int rb = 0; rb < 2; rb++) bg[rb] = Bm + (long)(n0 + rb * 32 + srow8) * 1024 + gkoff;

  auto stage = [&](int t) {   // 10 GLDS per thread-wave (8 A + 2 B)
    const int k0 = t * 64;
    char* Ab = (char*)&lds[t & 1][0];
    char* Bb = (char*)&lds[t & 1][16384];
#pragma unroll
    for (int ra = 0; ra < 8; ra++) GLDS16(ag[ra] + k0, Ab + tid * 16 + ra * 4096);
#pragma unroll
    for (int rb = 0; rb < 2; rb++) GLDS16(bg[rb] + k0, Bb + tid * 16 + rb * 4096);
  };

  auto compute = [&](int t) {
    const unsigned short* Ab = &lds[t & 1][0];
    const unsigned short* Bb = &lds[t & 1][16384];
    bf16x8 af[2][4], bf_[2][4];
#pragma unroll
    for (int ks = 0; ks < 2; ks++) {
#pragma unroll
      for (int i = 0; i < 4; i++) {
        const int rr = w * 64 + i * 16 + r16;
        af[ks][i] = *(const bf16x8*)(Ab + rr * 64 + (((ks * 4 + kb) ^ (rr & 7)) << 3));
      }
#pragma unroll
      for (int j = 0; j < 4; j++) {
        const int cc = j * 16 + r16;
        bf_[ks][j] = *(const bf16x8*)(Bb + cc * 64 + (((ks * 4 + kb) ^ (cc & 7)) << 3));
      }
    }
#pragma unroll
    for (int ks = 0; ks < 2; ks++)
#pragma unroll
      for (int i = 0; i < 4; i++)
#pragma unroll
        for (int j = 0; j < 4; j++)
          acc[i][j] = __builtin_amdgcn_mfma_f32_16x16x32_bf16(af[ks][i], bf_[ks][j], acc[i][j], 0, 0, 0);
  };

  stage(0);
  // Pipeline: iter t = { stage(t+1) [10 loads, stay in flight]; vmcnt(10)=stage(t) landed;
  // barrier (all waves' stage(t) visible); compute(t); raw barrier (buf reuse order, NO drain) }.
  // stage(t+2) is issued only after the 2nd barrier of iter t+1 -> never overwrites buf[t] early.
#pragma unroll 1
  for (int t = 0; t < 16; t++) {
    if (t < 15) {
      stage(t + 1);
      asm volatile("s_waitcnt vmcnt(10)" ::: "memory");
    } else {
      asm volatile("s_waitcnt vmcnt(0)" ::: "memory");
    }
    __builtin_amdgcn_s_barrier();
    __builtin_amdgcn_sched_barrier(0);   // keep ds_reads below the barrier (rule #18)
    compute(t);
    __builtin_amdgcn_sched_barrier(0);   // keep ds_reads above the reuse barrier
    __builtin_amdgcn_s_barrier();
  }

  // ---- in-register scan over t = 64w + 16i + 4h + q (C/D: col=lane&15, row=(lane>>4)*4+q) ----
  float a1[4], a2[4], a3[4], a4[4], a8[4], a12[4], a16[4], a64[4], p4h[4], r0v[4], Cw[4];
#pragma unroll
  for (int j = 0; j < 4; j++) {
    const int col = n0 + j * 16 + r16;
    const float a = alpha[col];
    a1[j] = a; a2[j] = a * a; a3[j] = a2[j] * a; a4[j] = a2[j] * a2[j];
    a8[j] = a4[j] * a4[j]; a12[j] = a8[j] * a4[j]; a16[j] = a8[j] * a8[j];
    const float a32 = a16[j] * a16[j]; a64[j] = a32 * a32;
    p4h[j] = (h == 0) ? 1.f : (h == 1) ? a4[j] : (h == 2) ? a8[j] : a12[j];
    r0v[j] = r0[b * 1024 + col];
    const float bb = bias[col];
    Cw[j] = 0.f;
#pragma unroll
    for (int i = 0; i < 4; i++) {
      const float u0 = acc[i][j][0] + bb, u1 = acc[i][j][1] + bb;
      const float u2 = acc[i][j][2] + bb, u3 = acc[i][j][3] + bb;
      const float l0 = u0;
      const float l1 = fmaf(a1[j], l0, u1);
      const float l2 = fmaf(a1[j], l1, u2);
      const float l3 = fmaf(a1[j], l2, u3);
      float xv = l3;
      float t1 = __shfl_up(xv, 16); if (h >= 1) xv = fmaf(a4[j], t1, xv);
      float t2 = __shfl_up(xv, 32); if (h >= 2) xv = fmaf(a8[j], t2, xv);
      float P  = __shfl_up(xv, 16); if (h == 0) P = 0.f;     // exclusive over h
      const float G = fmaf(p4h[j], Cw[j], P);                 // carry into (i,h)
      acc[i][j][0] = fmaf(a1[j], G, l0);
      acc[i][j][1] = fmaf(a2[j], G, l1);
      acc[i][j][2] = fmaf(a3[j], G, l2);
      acc[i][j][3] = fmaf(a4[j], G, l3);
      const float xe = __shfl(xv, r16 + 48);                  // inclusive at h=3
      Cw[j] = fmaf(a16[j], Cw[j], xe);                        // carry into frag i+1
    }
  }

  // ---- cross-wave combine via F[4][64] ----
  float* F = (float*)&lds[0][0];  // safe: past final loop barrier; scan was reg-only
  if (h == 0) {
#pragma unroll
    for (int j = 0; j < 4; j++) F[w * 64 + j * 16 + r16] = Cw[j];
  }
  __syncthreads();
  float R[4];
#pragma unroll
  for (int j = 0; j < 4; j++) {
    R[j] = r0v[j];
    for (int v = 0; v < w; v++) R[j] = fmaf(a64[j], R[j], F[v * 64 + j * 16 + r16]);
    float gi = p4h[j] * R[j];
#pragma unroll
    for (int i = 0; i < 4; i++) {
      acc[i][j][0] = fmaf(a1[j], gi, acc[i][j][0]);
      acc[i][j][1] = fmaf(a2[j], gi, acc[i][j][1]);
      acc[i][j][2] = fmaf(a3[j], gi, acc[i][j][2]);
      acc[i][j][3] = fmaf(a4[j], gi, acc[i][j][3]);
      gi *= a16[j];
    }
  }

  // ---- stores: r_seq ----
#pragma unroll
  for (int i = 0; i < 4; i++)
#pragma unroll
    for (int j = 0; j < 4; j++) {
      const long mrow = m0 + w * 64 + i * 16 + h * 4;
      const int  n    = n0 + j * 16 + r16;
#pragma unroll
      for (int q = 0; q < 4; q++)
        out[(mrow + q) * 1024 + n] = acc[i][j][q];
    }
  // r_final = a^64 R_2 + C_3 (wave 3 holds R_2 in R[j], C_3 in F[192+..])
  if (w == 3 && h == 0) {
#pragma unroll
    for (int j = 0; j < 4; j++)
      out[(1 << 22) + b * 1024 + n0 + j * 16 + r16] = fmaf(a64[j], R[j], F[192 + j * 16 + r16]);
  }
}

extern "C" void kernel_launch(void* const* d_in, const int* in_sizes, int n_in,
                              void* d_out, int out_size, void* d_ws, size_t ws_size,
                              hipStream_t stream) {
  const float* x     = (const float*)d_in[0];
  const float* r0    = (const float*)d_in[1];
  const float* W     = (const float*)d_in[2];
  const float* b     = (const float*)d_in[3];
  const float* alpha = (const float*)d_in[4];
  float* out = (float*)d_out;

  unsigned short* xm = (unsigned short*)d_ws;                        // 8 MiB: [4096][1024] bf16
  unsigned short* Wb = (unsigned short*)((char*)d_ws + (8u << 20));  // 2 MiB: [1024][1024] bf16

  k_mean<<<2048, 256, 0, stream>>>(x, xm, W, Wb);
  k_gemmscan<<<256, 256, 0, stream>>>(xm, Wb, b, r0, alpha, out);
}